// Round 9
// baseline (454.440 us; speedup 1.0000x reference)
//
#include <hip/hip_runtime.h>
#include <math.h>

#define NC 32
#define NI 32
#define NL 50
#define NQ 36
#define ND 1024
#define LAMBDA 9.0f

#define BM 128
#define BN 128

typedef __attribute__((ext_vector_type(8))) short bf16x8;
typedef __attribute__((ext_vector_type(4))) float floatx4;

static __device__ __forceinline__ unsigned short f2b(float f) {
    unsigned int u = __float_as_uint(f);
    unsigned int r = (u + 0x7fffu + ((u >> 16) & 1u)) >> 16;  // RNE
    return (unsigned short)r;
}
static __device__ __forceinline__ float bf2f(unsigned short u) {
    return __uint_as_float(((unsigned int)u) << 16);
}

// fast tanh: copysign(1 - 2/(e^{2|x|}+1), x); exact at 0, saturates to +-1
static __device__ __forceinline__ float ftanh(float x) {
    float ax = fabsf(x);
    float e = __expf(ax + ax);
    return copysignf(1.f - 2.f / (e + 1.f), x);
}

// async global->LDS, 16B/lane; LDS dest must be wave-uniform base + lane*16
static __device__ __forceinline__ void gload16(const unsigned short* g, unsigned short* l) {
    __builtin_amdgcn_global_load_lds(
        (const __attribute__((address_space(1))) unsigned int*)g,
        (__attribute__((address_space(3))) unsigned int*)l, 16, 0, 0);
}

// ---------------------------------------------------------------------------
// K0a: fp32 -> bf16 (4 weights)
// ---------------------------------------------------------------------------
struct CvtJob { const float* src; unsigned short* dst; int n2; int valid2; };
struct CvtJobs { CvtJob j[4]; };

__global__ __launch_bounds__(256) void k_cvt(CvtJobs jobs) {
    CvtJob jb = jobs.j[blockIdx.y];
    unsigned int* d32 = (unsigned int*)jb.dst;
    int stride = gridDim.x * 256;
    for (int i = blockIdx.x * 256 + threadIdx.x; i < jb.n2; i += stride) {
        unsigned int pk = 0;
        if (i < jb.valid2) {
            float2 v = ((const float2*)jb.src)[i];
            pk = (unsigned int)f2b(v.x) | ((unsigned int)f2b(v.y) << 16);
        }
        d32[i] = pk;
    }
}

// ---------------------------------------------------------------------------
// K0b: fp32 -> bf16 hi/lo split (x ~= hi + lo, lo = bf16(x - hi))
// ---------------------------------------------------------------------------
struct HlJob { const float* src; unsigned short* hi; unsigned short* lo; int n2; };
struct HlJobs { HlJob j[2]; };

__global__ __launch_bounds__(256) void k_cvt_hilo(HlJobs jobs) {
    HlJob jb = jobs.j[blockIdx.y];
    unsigned int* h32 = (unsigned int*)jb.hi;
    unsigned int* l32 = (unsigned int*)jb.lo;
    int stride = gridDim.x * 256;
    for (int i = blockIdx.x * 256 + threadIdx.x; i < jb.n2; i += stride) {
        float2 v = ((const float2*)jb.src)[i];
        unsigned short h0 = f2b(v.x), h1 = f2b(v.y);
        unsigned short l0 = f2b(v.x - bf2f(h0)), l1 = f2b(v.y - bf2f(h1));
        h32[i] = (unsigned int)h0 | ((unsigned int)h1 << 16);
        l32[i] = (unsigned int)l0 | ((unsigned int)l1 << 16);
    }
}

// ---------------------------------------------------------------------------
// K1a: S_big[1600][1152] = wrd . rgn^T as ONE GEMM (hi/lo: hh + hl + lh),
// 128x128x32 tiles, grid 9 x 13 = 117 blocks, 48 MFMA per barrier pair.
// A rows >= 1600 read adjacent workspace (garbage); stores guarded m < 1600.
// Per-K-step combo order (hh, hl, lh) matches the old k_attn -> bit-identical.
// ---------------------------------------------------------------------------
__global__ __launch_bounds__(256, 2) void k_sgemm(
    const unsigned short* __restrict__ Ah_, const unsigned short* __restrict__ Al_,
    const unsigned short* __restrict__ Bh_, const unsigned short* __restrict__ Bl_,
    float* __restrict__ Sb)
{
    const int K = ND;
    const int BK = 32;
    int bn = blockIdx.x, bm = blockIdx.y;
    int m0 = bm * 128, n0 = bn * 128;

    __shared__ __align__(16) unsigned short Aht[128 * 32], Alt[128 * 32];
    __shared__ __align__(16) unsigned short Bht[128 * 32], Blt[128 * 32];

    int t = threadIdx.x, lane = t & 63, wid = t >> 6;
    int wx = wid & 1, wy = wid >> 1;
    int lrow = lane & 15, quad = lane >> 4;
    floatx4 acc[4][4] = {};

    int srow = t >> 2, pos = t & 3;
    int ssw = (pos ^ ((srow >> 1) & 3)) * 8;
    const unsigned short* Ahp = Ah_ + (size_t)(m0 + srow) * K + ssw;
    const unsigned short* Alp = Al_ + (size_t)(m0 + srow) * K + ssw;
    const unsigned short* Bhp = Bh_ + (size_t)(n0 + srow) * K + ssw;
    const unsigned short* Blp = Bl_ + (size_t)(n0 + srow) * K + ssw;
    int dst0 = srow * BK + pos * 8;
    int fsw = (quad ^ ((lrow >> 1) & 3)) * 8;

    for (int kt = 0; kt < K; kt += BK) {
        gload16(Ahp + kt, &Aht[dst0]);
        gload16(Ahp + (size_t)64 * K + kt, &Aht[dst0 + 2048]);
        gload16(Alp + kt, &Alt[dst0]);
        gload16(Alp + (size_t)64 * K + kt, &Alt[dst0 + 2048]);
        gload16(Bhp + kt, &Bht[dst0]);
        gload16(Bhp + (size_t)64 * K + kt, &Bht[dst0 + 2048]);
        gload16(Blp + kt, &Blt[dst0]);
        gload16(Blp + (size_t)64 * K + kt, &Blt[dst0 + 2048]);
        __syncthreads();
        bf16x8 ah[4], al[4], bh[4], bl[4];
#pragma unroll
        for (int im = 0; im < 4; ++im) {
            ah[im] = *(const bf16x8*)&Aht[(wy * 64 + im * 16 + lrow) * BK + fsw];
            al[im] = *(const bf16x8*)&Alt[(wy * 64 + im * 16 + lrow) * BK + fsw];
        }
#pragma unroll
        for (int in = 0; in < 4; ++in) {
            bh[in] = *(const bf16x8*)&Bht[(wx * 64 + in * 16 + lrow) * BK + fsw];
            bl[in] = *(const bf16x8*)&Blt[(wx * 64 + in * 16 + lrow) * BK + fsw];
        }
#pragma unroll
        for (int im = 0; im < 4; ++im)
#pragma unroll
            for (int in = 0; in < 4; ++in) {
                acc[im][in] = __builtin_amdgcn_mfma_f32_16x16x32_bf16(
                    ah[im], bh[in], acc[im][in], 0, 0, 0);
                acc[im][in] = __builtin_amdgcn_mfma_f32_16x16x32_bf16(
                    ah[im], bl[in], acc[im][in], 0, 0, 0);
                acc[im][in] = __builtin_amdgcn_mfma_f32_16x16x32_bf16(
                    al[im], bh[in], acc[im][in], 0, 0, 0);
            }
        __syncthreads();
    }
    // fp32 store, guard m < 1600
#pragma unroll
    for (int im = 0; im < 4; ++im)
#pragma unroll
        for (int in = 0; in < 4; ++in) {
            int n = n0 + wx * 64 + in * 16 + lrow;
#pragma unroll
            for (int r = 0; r < 4; ++r) {
                int m = m0 + wy * 64 + im * 16 + quad * 4 + r;
                if (m < NC * NL) Sb[(size_t)m * (NI * NQ) + n] = acc[im][in][r];
            }
        }
}

// ---------------------------------------------------------------------------
// K1b: per-(c,i) leaky+L2-normalize+masked-softmax from S_big -> attn bf16.
// Same phase logic as the old k_attn tail (bit-identical math).
// ---------------------------------------------------------------------------
#define SST 37  // S LDS col stride

__global__ __launch_bounds__(256) void k_softmax(
    const float* __restrict__ Sb, const int* __restrict__ lens,
    unsigned short* __restrict__ attn)
{
    int bx = blockIdx.x;
    int c = bx / NI, i = bx % NI;
    __shared__ float S[NL * SST];
    int t = threadIdx.x;
    int len = lens[c];

    for (int idx = t; idx < NL * NQ; idx += 256) {
        int l = idx / NQ, q = idx - l * NQ;
        S[l * SST + q] = Sb[(size_t)(c * NL + l) * (NI * NQ) + i * NQ + q];
    }
    __syncthreads();
    // leaky + L2-normalize over q: 4 lanes per l, shuffle reduce
    if (t < 200) {
        int l = t >> 2, part = t & 3;
        float lv[9];
        float ss = 0.f;
#pragma unroll
        for (int jj = 0; jj < 9; ++jj) {
            int q = part * 9 + jj;
            float v = S[l * SST + q];
            float x = (v >= 0.f) ? v : 0.1f * v;
            lv[jj] = x;
            ss += x * x;
        }
        ss += __shfl_xor(ss, 1);
        ss += __shfl_xor(ss, 2);
        float inv = LAMBDA / fmaxf(sqrtf(ss), 1e-12f);
#pragma unroll
        for (int jj = 0; jj < 9; ++jj) S[l * SST + part * 9 + jj] = lv[jj] * inv;
    }
    __syncthreads();
    // masked softmax over l per q: 4 lanes per q, shuffle reduce
    if (t < 144) {
        int q = t >> 2, part = t & 3;
        int ls = part * 13;
        int le = ls + 13 < len ? ls + 13 : len;
        float m = -1e30f;
        for (int l = ls; l < le; ++l) m = fmaxf(m, S[l * SST + q]);
        m = fmaxf(m, __shfl_xor(m, 1));
        m = fmaxf(m, __shfl_xor(m, 2));
        float sum = 0.f;
        for (int l = ls; l < le; ++l) sum += __expf(S[l * SST + q] - m);
        sum += __shfl_xor(sum, 1);
        sum += __shfl_xor(sum, 2);
        float inv = 1.f / sum;
        unsigned int* o = (unsigned int*)attn + ((size_t)(c * NI + i) * NQ + q) * 32;
        int jb = part * 8;
#pragma unroll
        for (int jj = 0; jj < 8; ++jj) {
            int j = jb + jj;
            int l0 = 2 * j, l1 = 2 * j + 1;
            unsigned short a0 = (l0 < len) ? f2b(__expf(S[l0 * SST + q] - m) * inv) : (unsigned short)0;
            unsigned short a1 = (l1 < len) ? f2b(__expf(S[l1 * SST + q] - m) * inv) : (unsigned short)0;
            o[j] = (unsigned int)a0 | ((unsigned int)a1 << 16);
        }
    }
}

// ---------------------------------------------------------------------------
// K2: P_t[c][n][l64] = wrd_hi(1664xK) . W(NxK)^T, transposed scatter store.
// ---------------------------------------------------------------------------
__global__ __launch_bounds__(256, 2) void k_pgemm(
    const unsigned short* __restrict__ A, const unsigned short* __restrict__ B1,
    const unsigned short* __restrict__ B2, unsigned short* __restrict__ P1,
    unsigned short* __restrict__ P2)
{
    const int K = ND;
    const int BK = 32;
    int bn = blockIdx.x, bm = blockIdx.y;
    const unsigned short* B = blockIdx.z ? B2 : B1;
    unsigned short* P = blockIdx.z ? P2 : P1;
    int m0 = bm * BM, n0 = bn * BN;

    __shared__ __align__(16) unsigned short At[BM * 32];
    __shared__ __align__(16) unsigned short Bt[BN * 32];

    int t = threadIdx.x, lane = t & 63, wid = t >> 6;
    int wx = wid & 1, wy = wid >> 1;
    int lrow = lane & 15, quad = lane >> 4;
    floatx4 acc[4][4] = {};

    int srow = t >> 2, pos = t & 3;
    int ssw = (pos ^ ((srow >> 1) & 3)) * 8;
    const unsigned short* Aptr = A + (size_t)(m0 + srow) * K + ssw;
    const unsigned short* Bptr = B + (size_t)(n0 + srow) * K + ssw;
    unsigned short* Al  = &At[srow * BK + pos * 8];
    unsigned short* Al2 = &At[(srow + 64) * BK + pos * 8];
    unsigned short* Bl  = &Bt[srow * BK + pos * 8];
    unsigned short* Bl2 = &Bt[(srow + 64) * BK + pos * 8];
    int fsw = (quad ^ ((lrow >> 1) & 3)) * 8;

    for (int kt = 0; kt < K; kt += BK) {
        gload16(Aptr + kt, Al);
        gload16(Aptr + (size_t)64 * K + kt, Al2);
        gload16(Bptr + kt, Bl);
        gload16(Bptr + (size_t)64 * K + kt, Bl2);
        __syncthreads();
        bf16x8 af[4], bfr[4];
#pragma unroll
        for (int im = 0; im < 4; ++im)
            af[im] = *(const bf16x8*)&At[(wy * 64 + im * 16 + lrow) * BK + fsw];
#pragma unroll
        for (int in = 0; in < 4; ++in)
            bfr[in] = *(const bf16x8*)&Bt[(wx * 64 + in * 16 + lrow) * BK + fsw];
#pragma unroll
        for (int im = 0; im < 4; ++im)
#pragma unroll
            for (int in = 0; in < 4; ++in)
                acc[im][in] = __builtin_amdgcn_mfma_f32_16x16x32_bf16(
                    af[im], bfr[in], acc[im][in], 0, 0, 0);
        __syncthreads();
    }
    // transposed scatter: row m -> (c = m/50, l = m%50); store P[c][n][l]
#pragma unroll
    for (int im = 0; im < 4; ++im)
#pragma unroll
        for (int in = 0; in < 4; ++in) {
            int n = n0 + wx * 64 + in * 16 + lrow;
#pragma unroll
            for (int r = 0; r < 4; ++r) {
                int m = m0 + wy * 64 + im * 16 + quad * 4 + r;
                int c = m / NL, l = m - c * NL;
                if (c < NC) P[((size_t)(c * ND + n)) * 64 + l] = f2b(acc[im][in][r]);
            }
        }
}

// ---------------------------------------------------------------------------
// K3: batched K=64 dual GEMM + FiLM epilogue (fast tanh).
// Stores xbuf in (i,c,q) row order via LDS-packed full-line 16B stores.
// ---------------------------------------------------------------------------
__global__ __launch_bounds__(256, 2) void k_attn_gemm(
    const unsigned short* __restrict__ attn, const unsigned short* __restrict__ Psc,
    const unsigned short* __restrict__ Psh, const float* __restrict__ bsc,
    const float* __restrict__ bsh, const float* __restrict__ rgnf,
    unsigned short* __restrict__ xbuf)
{
    int bn = blockIdx.x, bm = blockIdx.y, c = blockIdx.z;
    __shared__ __align__(16) unsigned short smem3[3 * 128 * 64];
    unsigned short* At  = smem3;
    unsigned short* B1t = smem3 + 8192;
    unsigned short* B2t = smem3 + 16384;
    unsigned short* Ct  = smem3;          // 32KB epilogue overlay (At+B1t)
    int t = threadIdx.x, lane = t & 63, wid = t >> 6;
    int wx = wid & 1, wy = wid >> 1;
    int lrow = lane & 15, quad = lane >> 4;
    int grow = lane >> 3, pos = lane & 7;

    const unsigned short* Ab  = attn + (size_t)(c * 1152 + bm * 128) * 64;
    const unsigned short* B1b = Psc + (size_t)(c * ND + bn * 128) * 64;
    const unsigned short* B2b = Psh + (size_t)(c * ND + bn * 128) * 64;
    for (int g = wid; g < 16; g += 4) {
        int row = g * 8 + grow;
        int ssw = (pos ^ (row & 7)) * 8;
        gload16(Ab + (size_t)row * 64 + ssw, &At[g * 512 + lane * 8]);
        gload16(B1b + (size_t)row * 64 + ssw, &B1t[g * 512 + lane * 8]);
        gload16(B2b + (size_t)row * 64 + ssw, &B2t[g * 512 + lane * 8]);
    }
    __syncthreads();

    floatx4 acc[4][4] = {}, acc2[4][4] = {};
#pragma unroll
    for (int kk = 0; kk < 2; ++kk) {
        int sw = ((kk * 4 + quad) ^ (lrow & 7)) * 8;
        bf16x8 af[4], b1f[4], b2f[4];
#pragma unroll
        for (int im = 0; im < 4; ++im)
            af[im] = *(const bf16x8*)&At[(wy * 64 + im * 16 + lrow) * 64 + sw];
#pragma unroll
        for (int in = 0; in < 4; ++in) {
            b1f[in] = *(const bf16x8*)&B1t[(wx * 64 + in * 16 + lrow) * 64 + sw];
            b2f[in] = *(const bf16x8*)&B2t[(wx * 64 + in * 16 + lrow) * 64 + sw];
        }
#pragma unroll
        for (int im = 0; im < 4; ++im)
#pragma unroll
            for (int in = 0; in < 4; ++in) {
                acc[im][in] = __builtin_amdgcn_mfma_f32_16x16x32_bf16(
                    af[im], b1f[in], acc[im][in], 0, 0, 0);
                acc2[im][in] = __builtin_amdgcn_mfma_f32_16x16x32_bf16(
                    af[im], b2f[in], acc2[im][in], 0, 0, 0);
            }
    }
    __syncthreads();  // all LDS reads done before Ct overlay
#pragma unroll
    for (int im = 0; im < 4; ++im)
#pragma unroll
        for (int in = 0; in < 4; ++in) {
            int n = bn * 128 + wx * 64 + in * 16 + lrow;
            float b1v = bsc[n], b2v = bsh[n];
#pragma unroll
            for (int r = 0; r < 4; ++r) {
                int row = wy * 64 + im * 16 + quad * 4 + r;
                int m = bm * 128 + row;                    // < 1152, m = i*NQ+q
                int i = m / NQ, q = m - i * NQ;
                float sc = ftanh(acc[im][in][r] + b1v);
                float sh = acc2[im][in][r] + b2v;
                float rg = rgnf[(size_t)(i * NQ + q) * ND + n];
                int colc = (wx * 8 + in * 2 + (lrow >> 3)) ^ (row & 7);
                Ct[row * 128 + colc * 8 + (lrow & 7)] = f2b(rg * sc + sh);
            }
        }
    __syncthreads();
    // packed full-line stores, xbuf row' = (i*NC + c)*NQ + q
#pragma unroll
    for (int p = 0; p < 8; ++p) {
        int row = p * 16 + (t >> 4), chunk = t & 15;
        int m = bm * 128 + row;
        int i = m / NQ, q = m - i * NQ;
        size_t dr = ((size_t)(i * NC + c) * NQ + q) * ND + bn * 128 + chunk * 8;
        *(bf16x8*)&xbuf[dr] = *(const bf16x8*)&Ct[row * 128 + ((chunk ^ (row & 7)) * 8)];
    }
}

// ---------------------------------------------------------------------------
// Main MFMA GEMM, 128x128 tile, BK=64 (16 iterations), single-buffered 32KB
// LDS, source-swizzled (R5-measured config: ~86us/dispatch ~= m97 ceiling;
// explicit dbuf regressed via occupancy, R6).
// Rows of A/out are in (i,c,q) order (xbuf/hbuf layout).
// MODE 1: h = relu(A.B1^T + b1) (bf16), LDS-packed full-line stores.
// MODE 2: out[m] = A.B1^T + b1 + rgn[i,q]  (fp32, direct row store).
// XCD-grouped swizzle: 2304 blocks; bm = xcd*36 + k/8, bn = k%8.
// ---------------------------------------------------------------------------
template <int MODE, int MINW>
__global__ __launch_bounds__(256, MINW) void k_gemm(
    const unsigned short* __restrict__ A, const unsigned short* __restrict__ B1,
    const float* __restrict__ bias1, const float* __restrict__ rgnf,
    void* __restrict__ outp)
{
    const int K = ND;
    int lin = blockIdx.x;
    int xcd = lin & 7;
    int kb = lin >> 3;               // 0..287 within XCD
    int bm = xcd * 36 + (kb >> 3);   // 288 A-panels, 36 per XCD
    int bn = kb & 7;                 // 8 B-panels
    int m0 = bm * BM, n0 = bn * BN;

    __shared__ __align__(16) unsigned short smem[2 * 128 * 64];
    unsigned short* At = smem;            // [128][64]
    unsigned short* Bt = smem + 8192;     // [128][64]
    unsigned short* Ct = smem;            // 32KB epilogue overlay (MODE 1)

    int t = threadIdx.x;
    int lane = t & 63, wid = t >> 6;
    int wx = wid & 1, wy = wid >> 1;
    int lrow = lane & 15, quad = lane >> 4;

    floatx4 acc[4][4] = {};

    // staging: 256 thr x 16B = 32 rows/pass, 4 passes per matrix; source-swizzled
    int srow = t >> 3, pos = t & 7;
    int ssw = (pos ^ (srow & 7)) * 8;
    const unsigned short* Aptr  = A  + (size_t)(m0 + srow) * K + ssw;
    const unsigned short* B1ptr = B1 + (size_t)(n0 + srow) * K + ssw;
    unsigned short* ldA = At + t * 8;
    unsigned short* ldB = Bt + t * 8;

    for (int kt = 0; kt < K; kt += 64) {
#pragma unroll
        for (int p = 0; p < 4; ++p) {
            gload16(Aptr + (size_t)(p * 32) * K + kt, ldA + p * 2048);
            gload16(B1ptr + (size_t)(p * 32) * K + kt, ldB + p * 2048);
        }
        __syncthreads();
#pragma unroll
        for (int kh = 0; kh < 2; ++kh) {
            int sw = ((kh * 4 + quad) ^ (lrow & 7)) * 8;
            bf16x8 af[4], bfr[4];
#pragma unroll
            for (int im = 0; im < 4; ++im)
                af[im] = *(const bf16x8*)&At[(wy * 64 + im * 16 + lrow) * 64 + sw];
#pragma unroll
            for (int in = 0; in < 4; ++in)
                bfr[in] = *(const bf16x8*)&Bt[(wx * 64 + in * 16 + lrow) * 64 + sw];
#pragma unroll
            for (int im = 0; im < 4; ++im)
#pragma unroll
                for (int in = 0; in < 4; ++in)
                    acc[im][in] = __builtin_amdgcn_mfma_f32_16x16x32_bf16(
                        af[im], bfr[in], acc[im][in], 0, 0, 0);
        }
        __syncthreads();
    }

    // epilogue: C/D layout col = lane&15, row = quad*4 + reg  [m89/m91]
    if constexpr (MODE == 1) {
        // relu + bf16 -> Ct (swizzled), then packed full-line stores
#pragma unroll
        for (int im = 0; im < 4; ++im)
#pragma unroll
            for (int in = 0; in < 4; ++in) {
                int n = n0 + wx * 64 + in * 16 + lrow;
                float b1v = bias1[n];
#pragma unroll
                for (int r = 0; r < 4; ++r) {
                    int row = wy * 64 + im * 16 + quad * 4 + r;
                    float h = acc[im][in][r] + b1v;
                    h = h > 0.f ? h : 0.f;
                    int colc = (wx * 8 + in * 2 + (lrow >> 3)) ^ (row & 7);
                    Ct[row * 128 + colc * 8 + (lrow & 7)] = f2b(h);
                }
            }
        __syncthreads();
        unsigned short* ob = (unsigned short*)outp + (size_t)m0 * ND + n0;
#pragma unroll
        for (int p = 0; p < 8; ++p) {
            int row = p * 16 + (t >> 4), chunk = t & 15;
            *(bf16x8*)&ob[(size_t)row * ND + chunk * 8] =
                *(const bf16x8*)&Ct[row * 128 + ((chunk ^ (row & 7)) * 8)];
        }
    } else {
        // fp32 direct row store; rows are (i,c,q): i = m/1152, q = m%36
#pragma unroll
        for (int im = 0; im < 4; ++im)
#pragma unroll
            for (int in = 0; in < 4; ++in) {
                int n = n0 + wx * 64 + in * 16 + lrow;
                float b1v = bias1[n];
#pragma unroll
                for (int r = 0; r < 4; ++r) {
                    int m = m0 + wy * 64 + im * 16 + quad * 4 + r;
                    int i = m / (NC * NQ);
                    int q = m % NQ;
                    float rg = rgnf[(size_t)(i * NQ + q) * ND + n];
                    ((float*)outp)[(size_t)m * ND + n] = acc[im][in][r] + b1v + rg;
                }
            }
    }
}

extern "C" void kernel_launch(void* const* d_in, const int* in_sizes, int n_in,
                              void* d_out, int out_size, void* d_ws, size_t ws_size,
                              hipStream_t stream) {
    const float* rgn     = (const float*)d_in[0];
    const float* wrd     = (const float*)d_in[2];
    const int*   lens    = (const int*)d_in[4];
    const float* w_scale = (const float*)d_in[5];
    const float* b_scale = (const float*)d_in[6];
    const float* w_shift = (const float*)d_in[7];
    const float* b_shift = (const float*)d_in[8];
    const float* w1      = (const float*)d_in[9];
    const float* b1      = (const float*)d_in[10];
    const float* w2      = (const float*)d_in[11];
    const float* b2      = (const float*)d_in[12];
    float* outf = (float*)d_out;

    // workspace layout (bytes):
    //   0         wsc_bf   2,097,152
    //   2097152   wsh_bf   2,097,152
    //   4194304   w1_bf    2,097,152
    //   6291456   w2_bf    2,097,152
    //  11796480   attn     4,718,592  [c][i][q][l64]
    //  16515072   P_sct    4,194,304  [c][n][l64]
    //  20709376   P_sht    4,194,304
    //  24903680   wrd_hi   3,305,472  (sgemm/pgemm A; rows>=1600 spill wrd_lo)
    //  28209152   wrd_lo   3,305,472
    //  31514624   rgn_hi   2,383,872
    //  33898496   rgn_lo   2,383,872   -> scratch ends 36,282,368
    //  36282368   S_big    7,372,800  fp32 [1600][1152]  [dead after softmax]
    //   8388608   hbuf    75,497,472  (gemm1 output; overlaps dead regions)
    char* ws = (char*)d_ws;
    unsigned short* wsc_bf = (unsigned short*)(ws + 0);
    unsigned short* wsh_bf = (unsigned short*)(ws + 2097152);
    unsigned short* w1_bf  = (unsigned short*)(ws + 4194304);
    unsigned short* w2_bf  = (unsigned short*)(ws + 6291456);
    unsigned short* attn   = (unsigned short*)(ws + 11796480);
    unsigned short* P_sct  = (unsigned short*)(ws + 16515072);
    unsigned short* P_sht  = (unsigned short*)(ws + 20709376);
    unsigned short* wrd_hi = (unsigned short*)(ws + 24903680);
    unsigned short* wrd_lo = (unsigned short*)(ws + 28209152);
    unsigned short* rgn_hi = (unsigned short*)(ws + 31514624);
    unsigned short* rgn_lo = (unsigned short*)(ws + 33898496);
    float*          S_big  = (float*)(ws + 36282368);
    unsigned short* hbuf   = (unsigned short*)(ws + 8388608);
    unsigned short* xbuf   = (unsigned short*)d_out;  // bf16 x inside fp32 out buf

    CvtJobs jobs;
    jobs.j[0] = { w_scale, wsc_bf, ND * ND / 2, ND * ND / 2 };
    jobs.j[1] = { w_shift, wsh_bf, ND * ND / 2, ND * ND / 2 };
    jobs.j[2] = { w1,      w1_bf,  ND * ND / 2, ND * ND / 2 };
    jobs.j[3] = { w2,      w2_bf,  ND * ND / 2, ND * ND / 2 };
    k_cvt<<<dim3(128, 4), 256, 0, stream>>>(jobs);

    HlJobs hjobs;
    hjobs.j[0] = { wrd, wrd_hi, wrd_lo, NC * NL * ND / 2 };
    hjobs.j[1] = { rgn, rgn_hi, rgn_lo, NI * NQ * ND / 2 };
    k_cvt_hilo<<<dim3(128, 2), 256, 0, stream>>>(hjobs);

    // scores as one 1600x1152x1024 GEMM (9 x 13 tiles), then per-(c,i) softmax
    k_sgemm<<<dim3(9, 13), 256, 0, stream>>>(wrd_hi, wrd_lo, rgn_hi, rgn_lo, S_big);
    k_softmax<<<NC * NI, 256, 0, stream>>>(S_big, lens, attn);

    k_pgemm<<<dim3(8, 13, 2), 256, 0, stream>>>(wrd_hi, wsc_bf, wsh_bf, P_sct, P_sht);

    k_attn_gemm<<<dim3(8, 9, 32), 256, 0, stream>>>(attn, P_sct, P_sht,
                                                    b_scale, b_shift, rgn, xbuf);

    // 2304 blocks, XCD-grouped swizzle (decode inside kernel)
    k_gemm<1, 2><<<2304, 256, 0, stream>>>(xbuf, w1_bf, b1, rgn, hbuf);
    k_gemm<2, 2><<<2304, 256, 0, stream>>>(hbuf, w2_bf, b2, rgn, outf);
}

// Round 10
// 439.288 us; speedup vs baseline: 1.0345x; 1.0345x over previous
//
#include <hip/hip_runtime.h>
#include <math.h>

#define NC 32
#define NI 32
#define NL 50
#define NQ 36
#define ND 1024
#define LAMBDA 9.0f

#define BM 128
#define BN 128

typedef __attribute__((ext_vector_type(8))) short bf16x8;
typedef __attribute__((ext_vector_type(4))) float floatx4;

static __device__ __forceinline__ unsigned short f2b(float f) {
    unsigned int u = __float_as_uint(f);
    unsigned int r = (u + 0x7fffu + ((u >> 16) & 1u)) >> 16;  // RNE
    return (unsigned short)r;
}
static __device__ __forceinline__ float bf2f(unsigned short u) {
    return __uint_as_float(((unsigned int)u) << 16);
}

// fast tanh: copysign(1 - 2/(e^{2|x|}+1), x); exact at 0, saturates to +-1
static __device__ __forceinline__ float ftanh(float x) {
    float ax = fabsf(x);
    float e = __expf(ax + ax);
    return copysignf(1.f - 2.f / (e + 1.f), x);
}

// async global->LDS, 16B/lane; LDS dest must be wave-uniform base + lane*16
static __device__ __forceinline__ void gload16(const unsigned short* g, unsigned short* l) {
    __builtin_amdgcn_global_load_lds(
        (const __attribute__((address_space(1))) unsigned int*)g,
        (__attribute__((address_space(3))) unsigned int*)l, 16, 0, 0);
}

// ---------------------------------------------------------------------------
// K0: merged fp32->bf16 cvt (y=0..3: weights) + hi/lo split (y=4..5)
// ---------------------------------------------------------------------------
struct CvtJob { const float* src; unsigned short* dst; int n2; int valid2; };
struct CvtJobs { CvtJob j[4]; };
struct HlJob { const float* src; unsigned short* hi; unsigned short* lo; int n2; };
struct HlJobs { HlJob j[2]; };

__global__ __launch_bounds__(256) void k_cvt(CvtJobs jobs, HlJobs hjobs) {
    int y = blockIdx.y;
    int stride = gridDim.x * 256;
    if (y < 4) {
        CvtJob jb = jobs.j[y];
        unsigned int* d32 = (unsigned int*)jb.dst;
        for (int i = blockIdx.x * 256 + threadIdx.x; i < jb.n2; i += stride) {
            unsigned int pk = 0;
            if (i < jb.valid2) {
                float2 v = ((const float2*)jb.src)[i];
                pk = (unsigned int)f2b(v.x) | ((unsigned int)f2b(v.y) << 16);
            }
            d32[i] = pk;
        }
    } else {
        HlJob jb = hjobs.j[y - 4];
        unsigned int* h32 = (unsigned int*)jb.hi;
        unsigned int* l32 = (unsigned int*)jb.lo;
        for (int i = blockIdx.x * 256 + threadIdx.x; i < jb.n2; i += stride) {
            float2 v = ((const float2*)jb.src)[i];
            unsigned short h0 = f2b(v.x), h1 = f2b(v.y);
            unsigned short l0 = f2b(v.x - bf2f(h0)), l1 = f2b(v.y - bf2f(h1));
            h32[i] = (unsigned int)h0 | ((unsigned int)h1 << 16);
            l32[i] = (unsigned int)l0 | ((unsigned int)l1 << 16);
        }
    }
}

// ---------------------------------------------------------------------------
// K1: merged mid-kernel, 325 blocks.
//  blocks   0..116: S_big[1600][1152] = wrd . rgn^T (hi/lo: hh+hl+lh),
//                   128x128x32 tiles, bn = b%9, bm = b/9. 48 MFMA/barrier.
//  blocks 117..324: P_t[c][n][l64] = wrd_hi . {Wsc,Wsh}^T, 104 blocks each z.
// Both bodies read only cvt outputs and write disjoint buffers -> safe to
// co-schedule; separately each fills <half the 256 CUs.
// Shared 32KB static LDS (sgemm uses all 4 regions, pgemm the first 2).
// ---------------------------------------------------------------------------
__global__ __launch_bounds__(256, 2) void k_mid(
    const unsigned short* __restrict__ wrdh, const unsigned short* __restrict__ wrdl,
    const unsigned short* __restrict__ rgnh, const unsigned short* __restrict__ rgnl,
    const unsigned short* __restrict__ wsc, const unsigned short* __restrict__ wsh,
    float* __restrict__ Sb, unsigned short* __restrict__ P1,
    unsigned short* __restrict__ P2)
{
    const int K = ND;
    const int BK = 32;
    __shared__ __align__(16) unsigned short smem[4 * 4096];  // 32 KB

    int t = threadIdx.x, lane = t & 63, wid = t >> 6;
    int wx = wid & 1, wy = wid >> 1;
    int lrow = lane & 15, quad = lane >> 4;
    int srow = t >> 2, pos = t & 3;
    int ssw = (pos ^ ((srow >> 1) & 3)) * 8;
    int dst0 = srow * BK + pos * 8;
    int fsw = (quad ^ ((lrow >> 1) & 3)) * 8;
    int bid = blockIdx.x;

    if (bid < 117) {
        // ---- sgemm body: bn = bid % 9, bm = bid / 9 ----
        int bn = bid % 9, bm = bid / 9;
        int m0 = bm * 128, n0 = bn * 128;
        unsigned short* Aht = smem;
        unsigned short* Alt = smem + 4096;
        unsigned short* Bht = smem + 8192;
        unsigned short* Blt = smem + 12288;

        floatx4 acc[4][4] = {};
        const unsigned short* Ahp = wrdh + (size_t)(m0 + srow) * K + ssw;
        const unsigned short* Alp = wrdl + (size_t)(m0 + srow) * K + ssw;
        const unsigned short* Bhp = rgnh + (size_t)(n0 + srow) * K + ssw;
        const unsigned short* Blp = rgnl + (size_t)(n0 + srow) * K + ssw;

        for (int kt = 0; kt < K; kt += BK) {
            gload16(Ahp + kt, &Aht[dst0]);
            gload16(Ahp + (size_t)64 * K + kt, &Aht[dst0 + 2048]);
            gload16(Alp + kt, &Alt[dst0]);
            gload16(Alp + (size_t)64 * K + kt, &Alt[dst0 + 2048]);
            gload16(Bhp + kt, &Bht[dst0]);
            gload16(Bhp + (size_t)64 * K + kt, &Bht[dst0 + 2048]);
            gload16(Blp + kt, &Blt[dst0]);
            gload16(Blp + (size_t)64 * K + kt, &Blt[dst0 + 2048]);
            __syncthreads();
            bf16x8 ah[4], al[4], bh[4], bl[4];
#pragma unroll
            for (int im = 0; im < 4; ++im) {
                ah[im] = *(const bf16x8*)&Aht[(wy * 64 + im * 16 + lrow) * BK + fsw];
                al[im] = *(const bf16x8*)&Alt[(wy * 64 + im * 16 + lrow) * BK + fsw];
            }
#pragma unroll
            for (int in = 0; in < 4; ++in) {
                bh[in] = *(const bf16x8*)&Bht[(wx * 64 + in * 16 + lrow) * BK + fsw];
                bl[in] = *(const bf16x8*)&Blt[(wx * 64 + in * 16 + lrow) * BK + fsw];
            }
#pragma unroll
            for (int im = 0; im < 4; ++im)
#pragma unroll
                for (int in = 0; in < 4; ++in) {
                    acc[im][in] = __builtin_amdgcn_mfma_f32_16x16x32_bf16(
                        ah[im], bh[in], acc[im][in], 0, 0, 0);
                    acc[im][in] = __builtin_amdgcn_mfma_f32_16x16x32_bf16(
                        ah[im], bl[in], acc[im][in], 0, 0, 0);
                    acc[im][in] = __builtin_amdgcn_mfma_f32_16x16x32_bf16(
                        al[im], bh[in], acc[im][in], 0, 0, 0);
                }
            __syncthreads();
        }
#pragma unroll
        for (int im = 0; im < 4; ++im)
#pragma unroll
            for (int in = 0; in < 4; ++in) {
                int n = n0 + wx * 64 + in * 16 + lrow;
#pragma unroll
                for (int r = 0; r < 4; ++r) {
                    int m = m0 + wy * 64 + im * 16 + quad * 4 + r;
                    if (m < NC * NL) Sb[(size_t)m * (NI * NQ) + n] = acc[im][in][r];
                }
            }
    } else {
        // ---- pgemm body: r = bid-117; z = r/104; bn = (r%104)%8, bm = /8 ----
        int r0 = bid - 117;
        int z = r0 / 104;
        int rr = r0 - z * 104;
        int bn = rr & 7, bm = rr >> 3;
        const unsigned short* B = z ? wsh : wsc;
        unsigned short* P = z ? P2 : P1;
        int m0 = bm * BM, n0 = bn * BN;
        unsigned short* At = smem;
        unsigned short* Bt = smem + 4096;

        floatx4 acc[4][4] = {};
        const unsigned short* Aptr = wrdh + (size_t)(m0 + srow) * K + ssw;
        const unsigned short* Bptr = B + (size_t)(n0 + srow) * K + ssw;

        for (int kt = 0; kt < K; kt += BK) {
            gload16(Aptr + kt, &At[dst0]);
            gload16(Aptr + (size_t)64 * K + kt, &At[dst0 + 2048]);
            gload16(Bptr + kt, &Bt[dst0]);
            gload16(Bptr + (size_t)64 * K + kt, &Bt[dst0 + 2048]);
            __syncthreads();
            bf16x8 af[4], bfr[4];
#pragma unroll
            for (int im = 0; im < 4; ++im)
                af[im] = *(const bf16x8*)&At[(wy * 64 + im * 16 + lrow) * BK + fsw];
#pragma unroll
            for (int in = 0; in < 4; ++in)
                bfr[in] = *(const bf16x8*)&Bt[(wx * 64 + in * 16 + lrow) * BK + fsw];
#pragma unroll
            for (int im = 0; im < 4; ++im)
#pragma unroll
                for (int in = 0; in < 4; ++in)
                    acc[im][in] = __builtin_amdgcn_mfma_f32_16x16x32_bf16(
                        af[im], bfr[in], acc[im][in], 0, 0, 0);
            __syncthreads();
        }
        // transposed scatter: row m -> (c = m/50, l = m%50); store P[c][n][l]
#pragma unroll
        for (int im = 0; im < 4; ++im)
#pragma unroll
            for (int in = 0; in < 4; ++in) {
                int n = n0 + wx * 64 + in * 16 + lrow;
#pragma unroll
                for (int r = 0; r < 4; ++r) {
                    int m = m0 + wy * 64 + im * 16 + quad * 4 + r;
                    int c = m / NL, l = m - c * NL;
                    if (c < NC) P[((size_t)(c * ND + n)) * 64 + l] = f2b(acc[im][in][r]);
                }
            }
    }
}

// ---------------------------------------------------------------------------
// K1b: per-(c,i) leaky+L2-normalize+masked-softmax from S_big -> attn bf16.
// ---------------------------------------------------------------------------
#define SST 37  // S LDS col stride

__global__ __launch_bounds__(256) void k_softmax(
    const float* __restrict__ Sb, const int* __restrict__ lens,
    unsigned short* __restrict__ attn)
{
    int bx = blockIdx.x;
    int c = bx / NI, i = bx % NI;
    __shared__ float S[NL * SST];
    int t = threadIdx.x;
    int len = lens[c];

    for (int idx = t; idx < NL * NQ; idx += 256) {
        int l = idx / NQ, q = idx - l * NQ;
        S[l * SST + q] = Sb[(size_t)(c * NL + l) * (NI * NQ) + i * NQ + q];
    }
    __syncthreads();
    // leaky + L2-normalize over q: 4 lanes per l, shuffle reduce
    if (t < 200) {
        int l = t >> 2, part = t & 3;
        float lv[9];
        float ss = 0.f;
#pragma unroll
        for (int jj = 0; jj < 9; ++jj) {
            int q = part * 9 + jj;
            float v = S[l * SST + q];
            float x = (v >= 0.f) ? v : 0.1f * v;
            lv[jj] = x;
            ss += x * x;
        }
        ss += __shfl_xor(ss, 1);
        ss += __shfl_xor(ss, 2);
        float inv = LAMBDA / fmaxf(sqrtf(ss), 1e-12f);
#pragma unroll
        for (int jj = 0; jj < 9; ++jj) S[l * SST + part * 9 + jj] = lv[jj] * inv;
    }
    __syncthreads();
    // masked softmax over l per q: 4 lanes per q, shuffle reduce
    if (t < 144) {
        int q = t >> 2, part = t & 3;
        int ls = part * 13;
        int le = ls + 13 < len ? ls + 13 : len;
        float m = -1e30f;
        for (int l = ls; l < le; ++l) m = fmaxf(m, S[l * SST + q]);
        m = fmaxf(m, __shfl_xor(m, 1));
        m = fmaxf(m, __shfl_xor(m, 2));
        float sum = 0.f;
        for (int l = ls; l < le; ++l) sum += __expf(S[l * SST + q] - m);
        sum += __shfl_xor(sum, 1);
        sum += __shfl_xor(sum, 2);
        float inv = 1.f / sum;
        unsigned int* o = (unsigned int*)attn + ((size_t)(c * NI + i) * NQ + q) * 32;
        int jb = part * 8;
#pragma unroll
        for (int jj = 0; jj < 8; ++jj) {
            int j = jb + jj;
            int l0 = 2 * j, l1 = 2 * j + 1;
            unsigned short a0 = (l0 < len) ? f2b(__expf(S[l0 * SST + q] - m) * inv) : (unsigned short)0;
            unsigned short a1 = (l1 < len) ? f2b(__expf(S[l1 * SST + q] - m) * inv) : (unsigned short)0;
            o[j] = (unsigned int)a0 | ((unsigned int)a1 << 16);
        }
    }
}

// ---------------------------------------------------------------------------
// K3: batched K=64 dual GEMM + FiLM epilogue (fast tanh).
// Stores xbuf in (i,c,q) row order via LDS-packed full-line 16B stores.
// ---------------------------------------------------------------------------
__global__ __launch_bounds__(256, 2) void k_attn_gemm(
    const unsigned short* __restrict__ attn, const unsigned short* __restrict__ Psc,
    const unsigned short* __restrict__ Psh, const float* __restrict__ bsc,
    const float* __restrict__ bsh, const float* __restrict__ rgnf,
    unsigned short* __restrict__ xbuf)
{
    int bn = blockIdx.x, bm = blockIdx.y, c = blockIdx.z;
    __shared__ __align__(16) unsigned short smem3[3 * 128 * 64];
    unsigned short* At  = smem3;
    unsigned short* B1t = smem3 + 8192;
    unsigned short* B2t = smem3 + 16384;
    unsigned short* Ct  = smem3;          // 32KB epilogue overlay (At+B1t)
    int t = threadIdx.x, lane = t & 63, wid = t >> 6;
    int wx = wid & 1, wy = wid >> 1;
    int lrow = lane & 15, quad = lane >> 4;
    int grow = lane >> 3, pos = lane & 7;

    const unsigned short* Ab  = attn + (size_t)(c * 1152 + bm * 128) * 64;
    const unsigned short* B1b = Psc + (size_t)(c * ND + bn * 128) * 64;
    const unsigned short* B2b = Psh + (size_t)(c * ND + bn * 128) * 64;
    for (int g = wid; g < 16; g += 4) {
        int row = g * 8 + grow;
        int ssw = (pos ^ (row & 7)) * 8;
        gload16(Ab + (size_t)row * 64 + ssw, &At[g * 512 + lane * 8]);
        gload16(B1b + (size_t)row * 64 + ssw, &B1t[g * 512 + lane * 8]);
        gload16(B2b + (size_t)row * 64 + ssw, &B2t[g * 512 + lane * 8]);
    }
    __syncthreads();

    floatx4 acc[4][4] = {}, acc2[4][4] = {};
#pragma unroll
    for (int kk = 0; kk < 2; ++kk) {
        int sw = ((kk * 4 + quad) ^ (lrow & 7)) * 8;
        bf16x8 af[4], b1f[4], b2f[4];
#pragma unroll
        for (int im = 0; im < 4; ++im)
            af[im] = *(const bf16x8*)&At[(wy * 64 + im * 16 + lrow) * 64 + sw];
#pragma unroll
        for (int in = 0; in < 4; ++in) {
            b1f[in] = *(const bf16x8*)&B1t[(wx * 64 + in * 16 + lrow) * 64 + sw];
            b2f[in] = *(const bf16x8*)&B2t[(wx * 64 + in * 16 + lrow) * 64 + sw];
        }
#pragma unroll
        for (int im = 0; im < 4; ++im)
#pragma unroll
            for (int in = 0; in < 4; ++in) {
                acc[im][in] = __builtin_amdgcn_mfma_f32_16x16x32_bf16(
                    af[im], b1f[in], acc[im][in], 0, 0, 0);
                acc2[im][in] = __builtin_amdgcn_mfma_f32_16x16x32_bf16(
                    af[im], b2f[in], acc2[im][in], 0, 0, 0);
            }
    }
    __syncthreads();  // all LDS reads done before Ct overlay
#pragma unroll
    for (int im = 0; im < 4; ++im)
#pragma unroll
        for (int in = 0; in < 4; ++in) {
            int n = bn * 128 + wx * 64 + in * 16 + lrow;
            float b1v = bsc[n], b2v = bsh[n];
#pragma unroll
            for (int r = 0; r < 4; ++r) {
                int row = wy * 64 + im * 16 + quad * 4 + r;
                int m = bm * 128 + row;                    // < 1152, m = i*NQ+q
                int i = m / NQ, q = m - i * NQ;
                float sc = ftanh(acc[im][in][r] + b1v);
                float sh = acc2[im][in][r] + b2v;
                float rg = rgnf[(size_t)(i * NQ + q) * ND + n];
                int colc = (wx * 8 + in * 2 + (lrow >> 3)) ^ (row & 7);
                Ct[row * 128 + colc * 8 + (lrow & 7)] = f2b(rg * sc + sh);
            }
        }
    __syncthreads();
    // packed full-line stores, xbuf row' = (i*NC + c)*NQ + q
#pragma unroll
    for (int p = 0; p < 8; ++p) {
        int row = p * 16 + (t >> 4), chunk = t & 15;
        int m = bm * 128 + row;
        int i = m / NQ, q = m - i * NQ;
        size_t dr = ((size_t)(i * NC + c) * NQ + q) * ND + bn * 128 + chunk * 8;
        *(bf16x8*)&xbuf[dr] = *(const bf16x8*)&Ct[row * 128 + ((chunk ^ (row & 7)) * 8)];
    }
}

// ---------------------------------------------------------------------------
// Main MFMA GEMM, 128x128 tile, BK=64 (16 iterations), single-buffered 32KB
// LDS, source-swizzled (R5-measured config: ~86us/dispatch ~= m97 ceiling;
// explicit dbuf regressed via occupancy, R6).
// Rows of A/out are in (i,c,q) order (xbuf/hbuf layout).
// MODE 1: h = relu(A.B1^T + b1) (bf16), LDS-packed full-line stores.
// MODE 2: out[m] = A.B1^T + b1 + rgn[i,q]  (fp32, direct row store).
// XCD-grouped swizzle: 2304 blocks; bm = xcd*36 + k/8, bn = k%8.
// ---------------------------------------------------------------------------
template <int MODE, int MINW>
__global__ __launch_bounds__(256, MINW) void k_gemm(
    const unsigned short* __restrict__ A, const unsigned short* __restrict__ B1,
    const float* __restrict__ bias1, const float* __restrict__ rgnf,
    void* __restrict__ outp)
{
    const int K = ND;
    int lin = blockIdx.x;
    int xcd = lin & 7;
    int kb = lin >> 3;               // 0..287 within XCD
    int bm = xcd * 36 + (kb >> 3);   // 288 A-panels, 36 per XCD
    int bn = kb & 7;                 // 8 B-panels
    int m0 = bm * BM, n0 = bn * BN;

    __shared__ __align__(16) unsigned short smem[2 * 128 * 64];
    unsigned short* At = smem;            // [128][64]
    unsigned short* Bt = smem + 8192;     // [128][64]
    unsigned short* Ct = smem;            // 32KB epilogue overlay (MODE 1)

    int t = threadIdx.x;
    int lane = t & 63, wid = t >> 6;
    int wx = wid & 1, wy = wid >> 1;
    int lrow = lane & 15, quad = lane >> 4;

    floatx4 acc[4][4] = {};

    // staging: 256 thr x 16B = 32 rows/pass, 4 passes per matrix; source-swizzled
    int srow = t >> 3, pos = t & 7;
    int ssw = (pos ^ (srow & 7)) * 8;
    const unsigned short* Aptr  = A  + (size_t)(m0 + srow) * K + ssw;
    const unsigned short* B1ptr = B1 + (size_t)(n0 + srow) * K + ssw;
    unsigned short* ldA = At + t * 8;
    unsigned short* ldB = Bt + t * 8;

    for (int kt = 0; kt < K; kt += 64) {
#pragma unroll
        for (int p = 0; p < 4; ++p) {
            gload16(Aptr + (size_t)(p * 32) * K + kt, ldA + p * 2048);
            gload16(B1ptr + (size_t)(p * 32) * K + kt, ldB + p * 2048);
        }
        __syncthreads();
#pragma unroll
        for (int kh = 0; kh < 2; ++kh) {
            int sw = ((kh * 4 + quad) ^ (lrow & 7)) * 8;
            bf16x8 af[4], bfr[4];
#pragma unroll
            for (int im = 0; im < 4; ++im)
                af[im] = *(const bf16x8*)&At[(wy * 64 + im * 16 + lrow) * 64 + sw];
#pragma unroll
            for (int in = 0; in < 4; ++in)
                bfr[in] = *(const bf16x8*)&Bt[(wx * 64 + in * 16 + lrow) * 64 + sw];
#pragma unroll
            for (int im = 0; im < 4; ++im)
#pragma unroll
                for (int in = 0; in < 4; ++in)
                    acc[im][in] = __builtin_amdgcn_mfma_f32_16x16x32_bf16(
                        af[im], bfr[in], acc[im][in], 0, 0, 0);
        }
        __syncthreads();
    }

    // epilogue: C/D layout col = lane&15, row = quad*4 + reg  [m89/m91]
    if constexpr (MODE == 1) {
        // relu + bf16 -> Ct (swizzled), then packed full-line stores
#pragma unroll
        for (int im = 0; im < 4; ++im)
#pragma unroll
            for (int in = 0; in < 4; ++in) {
                int n = n0 + wx * 64 + in * 16 + lrow;
                float b1v = bias1[n];
#pragma unroll
                for (int r = 0; r < 4; ++r) {
                    int row = wy * 64 + im * 16 + quad * 4 + r;
                    float h = acc[im][in][r] + b1v;
                    h = h > 0.f ? h : 0.f;
                    int colc = (wx * 8 + in * 2 + (lrow >> 3)) ^ (row & 7);
                    Ct[row * 128 + colc * 8 + (lrow & 7)] = f2b(h);
                }
            }
        __syncthreads();
        unsigned short* ob = (unsigned short*)outp + (size_t)m0 * ND + n0;
#pragma unroll
        for (int p = 0; p < 8; ++p) {
            int row = p * 16 + (t >> 4), chunk = t & 15;
            *(bf16x8*)&ob[(size_t)row * ND + chunk * 8] =
                *(const bf16x8*)&Ct[row * 128 + ((chunk ^ (row & 7)) * 8)];
        }
    } else {
        // fp32 direct row store; rows are (i,c,q): i = m/1152, q = m%36
#pragma unroll
        for (int im = 0; im < 4; ++im)
#pragma unroll
            for (int in = 0; in < 4; ++in) {
                int n = n0 + wx * 64 + in * 16 + lrow;
                float b1v = bias1[n];
#pragma unroll
                for (int r = 0; r < 4; ++r) {
                    int m = m0 + wy * 64 + im * 16 + quad * 4 + r;
                    int i = m / (NC * NQ);
                    int q = m % NQ;
                    float rg = rgnf[(size_t)(i * NQ + q) * ND + n];
                    ((float*)outp)[(size_t)m * ND + n] = acc[im][in][r] + b1v + rg;
                }
            }
    }
}

extern "C" void kernel_launch(void* const* d_in, const int* in_sizes, int n_in,
                              void* d_out, int out_size, void* d_ws, size_t ws_size,
                              hipStream_t stream) {
    const float* rgn     = (const float*)d_in[0];
    const float* wrd     = (const float*)d_in[2];
    const int*   lens    = (const int*)d_in[4];
    const float* w_scale = (const float*)d_in[5];
    const float* b_scale = (const float*)d_in[6];
    const float* w_shift = (const float*)d_in[7];
    const float* b_shift = (const float*)d_in[8];
    const float* w1      = (const float*)d_in[9];
    const float* b1      = (const float*)d_in[10];
    const float* w2      = (const float*)d_in[11];
    const float* b2      = (const float*)d_in[12];
    float* outf = (float*)d_out;

    // workspace layout (bytes):
    //   0         wsc_bf   2,097,152
    //   2097152   wsh_bf   2,097,152
    //   4194304   w1_bf    2,097,152
    //   6291456   w2_bf    2,097,152
    //  11796480   attn     4,718,592  [c][i][q][l64]
    //  16515072   P_sct    4,194,304  [c][n][l64]
    //  20709376   P_sht    4,194,304
    //  24903680   wrd_hi   3,305,472  (mid A; rows>=1600 spill into wrd_lo)
    //  28209152   wrd_lo   3,305,472
    //  31514624   rgn_hi   2,383,872
    //  33898496   rgn_lo   2,383,872   -> scratch ends 36,282,368
    //  36282368   S_big    7,372,800  fp32 [1600][1152]  [dead after softmax]
    //   8388608   hbuf    75,497,472  (gemm1 output; overlaps dead regions)
    char* ws = (char*)d_ws;
    unsigned short* wsc_bf = (unsigned short*)(ws + 0);
    unsigned short* wsh_bf = (unsigned short*)(ws + 2097152);
    unsigned short* w1_bf  = (unsigned short*)(ws + 4194304);
    unsigned short* w2_bf  = (unsigned short*)(ws + 6291456);
    unsigned short* attn   = (unsigned short*)(ws + 11796480);
    unsigned short* P_sct  = (unsigned short*)(ws + 16515072);
    unsigned short* P_sht  = (unsigned short*)(ws + 20709376);
    unsigned short* wrd_hi = (unsigned short*)(ws + 24903680);
    unsigned short* wrd_lo = (unsigned short*)(ws + 28209152);
    unsigned short* rgn_hi = (unsigned short*)(ws + 31514624);
    unsigned short* rgn_lo = (unsigned short*)(ws + 33898496);
    float*          S_big  = (float*)(ws + 36282368);
    unsigned short* hbuf   = (unsigned short*)(ws + 8388608);
    unsigned short* xbuf   = (unsigned short*)d_out;  // bf16 x inside fp32 out buf

    CvtJobs jobs;
    jobs.j[0] = { w_scale, wsc_bf, ND * ND / 2, ND * ND / 2 };
    jobs.j[1] = { w_shift, wsh_bf, ND * ND / 2, ND * ND / 2 };
    jobs.j[2] = { w1,      w1_bf,  ND * ND / 2, ND * ND / 2 };
    jobs.j[3] = { w2,      w2_bf,  ND * ND / 2, ND * ND / 2 };
    HlJobs hjobs;
    hjobs.j[0] = { wrd, wrd_hi, wrd_lo, NC * NL * ND / 2 };
    hjobs.j[1] = { rgn, rgn_hi, rgn_lo, NI * NQ * ND / 2 };
    k_cvt<<<dim3(128, 6), 256, 0, stream>>>(jobs, hjobs);

    // merged: scores GEMM (117 blocks) + P GEMMs (208 blocks), co-scheduled
    k_mid<<<325, 256, 0, stream>>>(wrd_hi, wrd_lo, rgn_hi, rgn_lo,
                                   wsc_bf, wsh_bf, S_big, P_sct, P_sht);

    k_softmax<<<NC * NI, 256, 0, stream>>>(S_big, lens, attn);

    k_attn_gemm<<<dim3(8, 9, 32), 256, 0, stream>>>(attn, P_sct, P_sht,
                                                    b_scale, b_shift, rgn, xbuf);

    // 2304 blocks, XCD-grouped swizzle (decode inside kernel)
    k_gemm<1, 2><<<2304, 256, 0, stream>>>(xbuf, w1_bf, b1, rgn, hbuf);
    k_gemm<2, 2><<<2304, 256, 0, stream>>>(hbuf, w2_bf, b2, rgn, outf);
}

// Round 11
// 417.305 us; speedup vs baseline: 1.0890x; 1.0527x over previous
//
#include <hip/hip_runtime.h>
#include <math.h>

#define NC 32
#define NI 32
#define NL 50
#define NQ 36
#define ND 1024
#define LAMBDA 9.0f

#define BM 128
#define BN 128

typedef __attribute__((ext_vector_type(8))) short bf16x8;
typedef __attribute__((ext_vector_type(4))) float floatx4;

static __device__ __forceinline__ unsigned short f2b(float f) {
    unsigned int u = __float_as_uint(f);
    unsigned int r = (u + 0x7fffu + ((u >> 16) & 1u)) >> 16;  // RNE
    return (unsigned short)r;
}
static __device__ __forceinline__ float bf2f(unsigned short u) {
    return __uint_as_float(((unsigned int)u) << 16);
}

// fast tanh: copysign(1 - 2/(e^{2|x|}+1), x); exact at 0, saturates to +-1
static __device__ __forceinline__ float ftanh(float x) {
    float ax = fabsf(x);
    float e = __expf(ax + ax);
    return copysignf(1.f - 2.f / (e + 1.f), x);
}

// async global->LDS, 16B/lane; LDS dest must be wave-uniform base + lane*16
static __device__ __forceinline__ void gload16(const unsigned short* g, unsigned short* l) {
    __builtin_amdgcn_global_load_lds(
        (const __attribute__((address_space(1))) unsigned int*)g,
        (__attribute__((address_space(3))) unsigned int*)l, 16, 0, 0);
}

// ---------------------------------------------------------------------------
// K0: merged fp32->bf16 cvt (y=0..3: weights) + hi/lo split (y=4..5)
// ---------------------------------------------------------------------------
struct CvtJob { const float* src; unsigned short* dst; int n2; int valid2; };
struct CvtJobs { CvtJob j[4]; };
struct HlJob { const float* src; unsigned short* hi; unsigned short* lo; int n2; };
struct HlJobs { HlJob j[2]; };

__global__ __launch_bounds__(256) void k_cvt(CvtJobs jobs, HlJobs hjobs) {
    int y = blockIdx.y;
    int stride = gridDim.x * 256;
    if (y < 4) {
        CvtJob jb = jobs.j[y];
        unsigned int* d32 = (unsigned int*)jb.dst;
        for (int i = blockIdx.x * 256 + threadIdx.x; i < jb.n2; i += stride) {
            unsigned int pk = 0;
            if (i < jb.valid2) {
                float2 v = ((const float2*)jb.src)[i];
                pk = (unsigned int)f2b(v.x) | ((unsigned int)f2b(v.y) << 16);
            }
            d32[i] = pk;
        }
    } else {
        HlJob jb = hjobs.j[y - 4];
        unsigned int* h32 = (unsigned int*)jb.hi;
        unsigned int* l32 = (unsigned int*)jb.lo;
        for (int i = blockIdx.x * 256 + threadIdx.x; i < jb.n2; i += stride) {
            float2 v = ((const float2*)jb.src)[i];
            unsigned short h0 = f2b(v.x), h1 = f2b(v.y);
            unsigned short l0 = f2b(v.x - bf2f(h0)), l1 = f2b(v.y - bf2f(h1));
            h32[i] = (unsigned int)h0 | ((unsigned int)h1 << 16);
            l32[i] = (unsigned int)l0 | ((unsigned int)l1 << 16);
        }
    }
}

// ---------------------------------------------------------------------------
// K1: merged mid-kernel, 325 blocks.
//  blocks   0..116: S_big[1600][1152] = wrd . rgn^T (hi/lo: hh+hl+lh),
//                   128x128x32 tiles, bn = b%9, bm = b/9. 48 MFMA/barrier.
//  blocks 117..324: P_t[c][n][l64] = wrd_hi . {Wsc,Wsh}^T, 104 blocks each z.
// ---------------------------------------------------------------------------
__global__ __launch_bounds__(256, 2) void k_mid(
    const unsigned short* __restrict__ wrdh, const unsigned short* __restrict__ wrdl,
    const unsigned short* __restrict__ rgnh, const unsigned short* __restrict__ rgnl,
    const unsigned short* __restrict__ wsc, const unsigned short* __restrict__ wsh,
    float* __restrict__ Sb, unsigned short* __restrict__ P1,
    unsigned short* __restrict__ P2)
{
    const int K = ND;
    const int BK = 32;
    __shared__ __align__(16) unsigned short smem[4 * 4096];  // 32 KB

    int t = threadIdx.x, lane = t & 63, wid = t >> 6;
    int wx = wid & 1, wy = wid >> 1;
    int lrow = lane & 15, quad = lane >> 4;
    int srow = t >> 2, pos = t & 3;
    int ssw = (pos ^ ((srow >> 1) & 3)) * 8;
    int dst0 = srow * BK + pos * 8;
    int fsw = (quad ^ ((lrow >> 1) & 3)) * 8;
    int bid = blockIdx.x;

    if (bid < 117) {
        // ---- sgemm body: bn = bid % 9, bm = bid / 9 ----
        int bn = bid % 9, bm = bid / 9;
        int m0 = bm * 128, n0 = bn * 128;
        unsigned short* Aht = smem;
        unsigned short* Alt = smem + 4096;
        unsigned short* Bht = smem + 8192;
        unsigned short* Blt = smem + 12288;

        floatx4 acc[4][4] = {};
        const unsigned short* Ahp = wrdh + (size_t)(m0 + srow) * K + ssw;
        const unsigned short* Alp = wrdl + (size_t)(m0 + srow) * K + ssw;
        const unsigned short* Bhp = rgnh + (size_t)(n0 + srow) * K + ssw;
        const unsigned short* Blp = rgnl + (size_t)(n0 + srow) * K + ssw;

        for (int kt = 0; kt < K; kt += BK) {
            gload16(Ahp + kt, &Aht[dst0]);
            gload16(Ahp + (size_t)64 * K + kt, &Aht[dst0 + 2048]);
            gload16(Alp + kt, &Alt[dst0]);
            gload16(Alp + (size_t)64 * K + kt, &Alt[dst0 + 2048]);
            gload16(Bhp + kt, &Bht[dst0]);
            gload16(Bhp + (size_t)64 * K + kt, &Bht[dst0 + 2048]);
            gload16(Blp + kt, &Blt[dst0]);
            gload16(Blp + (size_t)64 * K + kt, &Blt[dst0 + 2048]);
            __syncthreads();
            bf16x8 ah[4], al[4], bh[4], bl[4];
#pragma unroll
            for (int im = 0; im < 4; ++im) {
                ah[im] = *(const bf16x8*)&Aht[(wy * 64 + im * 16 + lrow) * BK + fsw];
                al[im] = *(const bf16x8*)&Alt[(wy * 64 + im * 16 + lrow) * BK + fsw];
            }
#pragma unroll
            for (int in = 0; in < 4; ++in) {
                bh[in] = *(const bf16x8*)&Bht[(wx * 64 + in * 16 + lrow) * BK + fsw];
                bl[in] = *(const bf16x8*)&Blt[(wx * 64 + in * 16 + lrow) * BK + fsw];
            }
#pragma unroll
            for (int im = 0; im < 4; ++im)
#pragma unroll
                for (int in = 0; in < 4; ++in) {
                    acc[im][in] = __builtin_amdgcn_mfma_f32_16x16x32_bf16(
                        ah[im], bh[in], acc[im][in], 0, 0, 0);
                    acc[im][in] = __builtin_amdgcn_mfma_f32_16x16x32_bf16(
                        ah[im], bl[in], acc[im][in], 0, 0, 0);
                    acc[im][in] = __builtin_amdgcn_mfma_f32_16x16x32_bf16(
                        al[im], bh[in], acc[im][in], 0, 0, 0);
                }
            __syncthreads();
        }
#pragma unroll
        for (int im = 0; im < 4; ++im)
#pragma unroll
            for (int in = 0; in < 4; ++in) {
                int n = n0 + wx * 64 + in * 16 + lrow;
#pragma unroll
                for (int r = 0; r < 4; ++r) {
                    int m = m0 + wy * 64 + im * 16 + quad * 4 + r;
                    if (m < NC * NL) Sb[(size_t)m * (NI * NQ) + n] = acc[im][in][r];
                }
            }
    } else {
        // ---- pgemm body: r = bid-117; z = r/104; bn = (r%104)%8, bm = /8 ----
        int r0 = bid - 117;
        int z = r0 / 104;
        int rr = r0 - z * 104;
        int bn = rr & 7, bm = rr >> 3;
        const unsigned short* B = z ? wsh : wsc;
        unsigned short* P = z ? P2 : P1;
        int m0 = bm * BM, n0 = bn * BN;
        unsigned short* At = smem;
        unsigned short* Bt = smem + 4096;

        floatx4 acc[4][4] = {};
        const unsigned short* Aptr = wrdh + (size_t)(m0 + srow) * K + ssw;
        const unsigned short* Bptr = B + (size_t)(n0 + srow) * K + ssw;

        for (int kt = 0; kt < K; kt += BK) {
            gload16(Aptr + kt, &At[dst0]);
            gload16(Aptr + (size_t)64 * K + kt, &At[dst0 + 2048]);
            gload16(Bptr + kt, &Bt[dst0]);
            gload16(Bptr + (size_t)64 * K + kt, &Bt[dst0 + 2048]);
            __syncthreads();
            bf16x8 af[4], bfr[4];
#pragma unroll
            for (int im = 0; im < 4; ++im)
                af[im] = *(const bf16x8*)&At[(wy * 64 + im * 16 + lrow) * BK + fsw];
#pragma unroll
            for (int in = 0; in < 4; ++in)
                bfr[in] = *(const bf16x8*)&Bt[(wx * 64 + in * 16 + lrow) * BK + fsw];
#pragma unroll
            for (int im = 0; im < 4; ++im)
#pragma unroll
                for (int in = 0; in < 4; ++in)
                    acc[im][in] = __builtin_amdgcn_mfma_f32_16x16x32_bf16(
                        af[im], bfr[in], acc[im][in], 0, 0, 0);
            __syncthreads();
        }
        // transposed scatter: row m -> (c = m/50, l = m%50); store P[c][n][l]
#pragma unroll
        for (int im = 0; im < 4; ++im)
#pragma unroll
            for (int in = 0; in < 4; ++in) {
                int n = n0 + wx * 64 + in * 16 + lrow;
#pragma unroll
                for (int r = 0; r < 4; ++r) {
                    int m = m0 + wy * 64 + im * 16 + quad * 4 + r;
                    int c = m / NL, l = m - c * NL;
                    if (c < NC) P[((size_t)(c * ND + n)) * 64 + l] = f2b(acc[im][in][r]);
                }
            }
    }
}

// ---------------------------------------------------------------------------
// K1b: per-(c,i) leaky+L2-normalize+masked-softmax from S_big -> attn bf16.
// ---------------------------------------------------------------------------
#define SST 37  // S LDS col stride

__global__ __launch_bounds__(256) void k_softmax(
    const float* __restrict__ Sb, const int* __restrict__ lens,
    unsigned short* __restrict__ attn)
{
    int bx = blockIdx.x;
    int c = bx / NI, i = bx % NI;
    __shared__ float S[NL * SST];
    int t = threadIdx.x;
    int len = lens[c];

    for (int idx = t; idx < NL * NQ; idx += 256) {
        int l = idx / NQ, q = idx - l * NQ;
        S[l * SST + q] = Sb[(size_t)(c * NL + l) * (NI * NQ) + i * NQ + q];
    }
    __syncthreads();
    // leaky + L2-normalize over q: 4 lanes per l, shuffle reduce
    if (t < 200) {
        int l = t >> 2, part = t & 3;
        float lv[9];
        float ss = 0.f;
#pragma unroll
        for (int jj = 0; jj < 9; ++jj) {
            int q = part * 9 + jj;
            float v = S[l * SST + q];
            float x = (v >= 0.f) ? v : 0.1f * v;
            lv[jj] = x;
            ss += x * x;
        }
        ss += __shfl_xor(ss, 1);
        ss += __shfl_xor(ss, 2);
        float inv = LAMBDA / fmaxf(sqrtf(ss), 1e-12f);
#pragma unroll
        for (int jj = 0; jj < 9; ++jj) S[l * SST + part * 9 + jj] = lv[jj] * inv;
    }
    __syncthreads();
    // masked softmax over l per q: 4 lanes per q, shuffle reduce
    if (t < 144) {
        int q = t >> 2, part = t & 3;
        int ls = part * 13;
        int le = ls + 13 < len ? ls + 13 : len;
        float m = -1e30f;
        for (int l = ls; l < le; ++l) m = fmaxf(m, S[l * SST + q]);
        m = fmaxf(m, __shfl_xor(m, 1));
        m = fmaxf(m, __shfl_xor(m, 2));
        float sum = 0.f;
        for (int l = ls; l < le; ++l) sum += __expf(S[l * SST + q] - m);
        sum += __shfl_xor(sum, 1);
        sum += __shfl_xor(sum, 2);
        float inv = 1.f / sum;
        unsigned int* o = (unsigned int*)attn + ((size_t)(c * NI + i) * NQ + q) * 32;
        int jb = part * 8;
#pragma unroll
        for (int jj = 0; jj < 8; ++jj) {
            int j = jb + jj;
            int l0 = 2 * j, l1 = 2 * j + 1;
            unsigned short a0 = (l0 < len) ? f2b(__expf(S[l0 * SST + q] - m) * inv) : (unsigned short)0;
            unsigned short a1 = (l1 < len) ? f2b(__expf(S[l1 * SST + q] - m) * inv) : (unsigned short)0;
            o[j] = (unsigned int)a0 | ((unsigned int)a1 << 16);
        }
    }
}

// ---------------------------------------------------------------------------
// K3: batched K=64 dual GEMM + FiLM epilogue (fast tanh).
// Stores xbuf in (i,c,q) row order via LDS-packed full-line 16B stores.
// ---------------------------------------------------------------------------
__global__ __launch_bounds__(256, 2) void k_attn_gemm(
    const unsigned short* __restrict__ attn, const unsigned short* __restrict__ Psc,
    const unsigned short* __restrict__ Psh, const float* __restrict__ bsc,
    const float* __restrict__ bsh, const float* __restrict__ rgnf,
    unsigned short* __restrict__ xbuf)
{
    int bn = blockIdx.x, bm = blockIdx.y, c = blockIdx.z;
    __shared__ __align__(16) unsigned short smem3[3 * 128 * 64];
    unsigned short* At  = smem3;
    unsigned short* B1t = smem3 + 8192;
    unsigned short* B2t = smem3 + 16384;
    unsigned short* Ct  = smem3;          // 32KB epilogue overlay (At+B1t)
    int t = threadIdx.x, lane = t & 63, wid = t >> 6;
    int wx = wid & 1, wy = wid >> 1;
    int lrow = lane & 15, quad = lane >> 4;
    int grow = lane >> 3, pos = lane & 7;

    const unsigned short* Ab  = attn + (size_t)(c * 1152 + bm * 128) * 64;
    const unsigned short* B1b = Psc + (size_t)(c * ND + bn * 128) * 64;
    const unsigned short* B2b = Psh + (size_t)(c * ND + bn * 128) * 64;
    for (int g = wid; g < 16; g += 4) {
        int row = g * 8 + grow;
        int ssw = (pos ^ (row & 7)) * 8;
        gload16(Ab + (size_t)row * 64 + ssw, &At[g * 512 + lane * 8]);
        gload16(B1b + (size_t)row * 64 + ssw, &B1t[g * 512 + lane * 8]);
        gload16(B2b + (size_t)row * 64 + ssw, &B2t[g * 512 + lane * 8]);
    }
    __syncthreads();

    floatx4 acc[4][4] = {}, acc2[4][4] = {};
#pragma unroll
    for (int kk = 0; kk < 2; ++kk) {
        int sw = ((kk * 4 + quad) ^ (lrow & 7)) * 8;
        bf16x8 af[4], b1f[4], b2f[4];
#pragma unroll
        for (int im = 0; im < 4; ++im)
            af[im] = *(const bf16x8*)&At[(wy * 64 + im * 16 + lrow) * 64 + sw];
#pragma unroll
        for (int in = 0; in < 4; ++in) {
            b1f[in] = *(const bf16x8*)&B1t[(wx * 64 + in * 16 + lrow) * 64 + sw];
            b2f[in] = *(const bf16x8*)&B2t[(wx * 64 + in * 16 + lrow) * 64 + sw];
        }
#pragma unroll
        for (int im = 0; im < 4; ++im)
#pragma unroll
            for (int in = 0; in < 4; ++in) {
                acc[im][in] = __builtin_amdgcn_mfma_f32_16x16x32_bf16(
                    af[im], b1f[in], acc[im][in], 0, 0, 0);
                acc2[im][in] = __builtin_amdgcn_mfma_f32_16x16x32_bf16(
                    af[im], b2f[in], acc2[im][in], 0, 0, 0);
            }
    }
    __syncthreads();  // all LDS reads done before Ct overlay
#pragma unroll
    for (int im = 0; im < 4; ++im)
#pragma unroll
        for (int in = 0; in < 4; ++in) {
            int n = bn * 128 + wx * 64 + in * 16 + lrow;
            float b1v = bsc[n], b2v = bsh[n];
#pragma unroll
            for (int r = 0; r < 4; ++r) {
                int row = wy * 64 + im * 16 + quad * 4 + r;
                int m = bm * 128 + row;                    // < 1152, m = i*NQ+q
                int i = m / NQ, q = m - i * NQ;
                float sc = ftanh(acc[im][in][r] + b1v);
                float sh = acc2[im][in][r] + b2v;
                float rg = rgnf[(size_t)(i * NQ + q) * ND + n];
                int colc = (wx * 8 + in * 2 + (lrow >> 3)) ^ (row & 7);
                Ct[row * 128 + colc * 8 + (lrow & 7)] = f2b(rg * sc + sh);
            }
        }
    __syncthreads();
    // packed full-line stores, xbuf row' = (i*NC + c)*NQ + q
#pragma unroll
    for (int p = 0; p < 8; ++p) {
        int row = p * 16 + (t >> 4), chunk = t & 15;
        int m = bm * 128 + row;
        int i = m / NQ, q = m - i * NQ;
        size_t dr = ((size_t)(i * NC + c) * NQ + q) * ND + bn * 128 + chunk * 8;
        *(bf16x8*)&xbuf[dr] = *(const bf16x8*)&Ct[row * 128 + ((chunk ^ (row & 7)) * 8)];
    }
}

// ---------------------------------------------------------------------------
// Main MFMA GEMM, 128x128 tile, BK=64 (16 iterations), single-buffered 32KB
// LDS, source-swizzled.  MINW=4 this round: __launch_bounds__(256,4) forces
// total regs <= 128 (64 acc AGPR + ~56 VGPR) -> 4 blocks/CU instead of ~3
// (occupancy steps at 128 regs, m69). Watch for spills; revert if regressed.
// MODE 1: h = relu(A.B1^T + b1) (bf16), LDS-packed full-line stores.
// MODE 2: out[m] = A.B1^T + b1 + rgn[i,q]  (fp32, direct row store).
// XCD-grouped swizzle: 2304 blocks; bm = xcd*36 + k/8, bn = k%8.
// ---------------------------------------------------------------------------
template <int MODE, int MINW>
__global__ __launch_bounds__(256, MINW) void k_gemm(
    const unsigned short* __restrict__ A, const unsigned short* __restrict__ B1,
    const float* __restrict__ bias1, const float* __restrict__ rgnf,
    void* __restrict__ outp)
{
    const int K = ND;
    int lin = blockIdx.x;
    int xcd = lin & 7;
    int kb = lin >> 3;               // 0..287 within XCD
    int bm = xcd * 36 + (kb >> 3);   // 288 A-panels, 36 per XCD
    int bn = kb & 7;                 // 8 B-panels
    int m0 = bm * BM, n0 = bn * BN;

    __shared__ __align__(16) unsigned short smem[2 * 128 * 64];
    unsigned short* At = smem;            // [128][64]
    unsigned short* Bt = smem + 8192;     // [128][64]
    unsigned short* Ct = smem;            // 32KB epilogue overlay (MODE 1)

    int t = threadIdx.x;
    int lane = t & 63, wid = t >> 6;
    int wx = wid & 1, wy = wid >> 1;
    int lrow = lane & 15, quad = lane >> 4;

    floatx4 acc[4][4] = {};

    // staging: 256 thr x 16B = 32 rows/pass, 4 passes per matrix; source-swizzled
    int srow = t >> 3, pos = t & 7;
    int ssw = (pos ^ (srow & 7)) * 8;
    const unsigned short* Aptr  = A  + (size_t)(m0 + srow) * K + ssw;
    const unsigned short* B1ptr = B1 + (size_t)(n0 + srow) * K + ssw;
    unsigned short* ldA = At + t * 8;
    unsigned short* ldB = Bt + t * 8;

    for (int kt = 0; kt < K; kt += 64) {
#pragma unroll
        for (int p = 0; p < 4; ++p) {
            gload16(Aptr + (size_t)(p * 32) * K + kt, ldA + p * 2048);
            gload16(B1ptr + (size_t)(p * 32) * K + kt, ldB + p * 2048);
        }
        __syncthreads();
#pragma unroll
        for (int kh = 0; kh < 2; ++kh) {
            int sw = ((kh * 4 + quad) ^ (lrow & 7)) * 8;
            bf16x8 af[4], bfr[4];
#pragma unroll
            for (int im = 0; im < 4; ++im)
                af[im] = *(const bf16x8*)&At[(wy * 64 + im * 16 + lrow) * 64 + sw];
#pragma unroll
            for (int in = 0; in < 4; ++in)
                bfr[in] = *(const bf16x8*)&Bt[(wx * 64 + in * 16 + lrow) * 64 + sw];
#pragma unroll
            for (int im = 0; im < 4; ++im)
#pragma unroll
                for (int in = 0; in < 4; ++in)
                    acc[im][in] = __builtin_amdgcn_mfma_f32_16x16x32_bf16(
                        af[im], bfr[in], acc[im][in], 0, 0, 0);
        }
        __syncthreads();
    }

    // epilogue: C/D layout col = lane&15, row = quad*4 + reg  [m89/m91]
    if constexpr (MODE == 1) {
        // relu + bf16 -> Ct (swizzled), then packed full-line stores
#pragma unroll
        for (int im = 0; im < 4; ++im)
#pragma unroll
            for (int in = 0; in < 4; ++in) {
                int n = n0 + wx * 64 + in * 16 + lrow;
                float b1v = bias1[n];
#pragma unroll
                for (int r = 0; r < 4; ++r) {
                    int row = wy * 64 + im * 16 + quad * 4 + r;
                    float h = acc[im][in][r] + b1v;
                    h = h > 0.f ? h : 0.f;
                    int colc = (wx * 8 + in * 2 + (lrow >> 3)) ^ (row & 7);
                    Ct[row * 128 + colc * 8 + (lrow & 7)] = f2b(h);
                }
            }
        __syncthreads();
        unsigned short* ob = (unsigned short*)outp + (size_t)m0 * ND + n0;
#pragma unroll
        for (int p = 0; p < 8; ++p) {
            int row = p * 16 + (t >> 4), chunk = t & 15;
            *(bf16x8*)&ob[(size_t)row * ND + chunk * 8] =
                *(const bf16x8*)&Ct[row * 128 + ((chunk ^ (row & 7)) * 8)];
        }
    } else {
        // fp32 direct row store; rows are (i,c,q): i = m/1152, q = m%36
#pragma unroll
        for (int im = 0; im < 4; ++im)
#pragma unroll
            for (int in = 0; in < 4; ++in) {
                int n = n0 + wx * 64 + in * 16 + lrow;
                float b1v = bias1[n];
#pragma unroll
                for (int r = 0; r < 4; ++r) {
                    int m = m0 + wy * 64 + im * 16 + quad * 4 + r;
                    int i = m / (NC * NQ);
                    int q = m % NQ;
                    float rg = rgnf[(size_t)(i * NQ + q) * ND + n];
                    ((float*)outp)[(size_t)m * ND + n] = acc[im][in][r] + b1v + rg;
                }
            }
    }
}

extern "C" void kernel_launch(void* const* d_in, const int* in_sizes, int n_in,
                              void* d_out, int out_size, void* d_ws, size_t ws_size,
                              hipStream_t stream) {
    const float* rgn     = (const float*)d_in[0];
    const float* wrd     = (const float*)d_in[2];
    const int*   lens    = (const int*)d_in[4];
    const float* w_scale = (const float*)d_in[5];
    const float* b_scale = (const float*)d_in[6];
    const float* w_shift = (const float*)d_in[7];
    const float* b_shift = (const float*)d_in[8];
    const float* w1      = (const float*)d_in[9];
    const float* b1      = (const float*)d_in[10];
    const float* w2      = (const float*)d_in[11];
    const float* b2      = (const float*)d_in[12];
    float* outf = (float*)d_out;

    // workspace layout (bytes):
    //   0         wsc_bf   2,097,152
    //   2097152   wsh_bf   2,097,152
    //   4194304   w1_bf    2,097,152
    //   6291456   w2_bf    2,097,152
    //  11796480   attn     4,718,592  [c][i][q][l64]
    //  16515072   P_sct    4,194,304  [c][n][l64]
    //  20709376   P_sht    4,194,304
    //  24903680   wrd_hi   3,305,472  (mid A; rows>=1600 spill into wrd_lo)
    //  28209152   wrd_lo   3,305,472
    //  31514624   rgn_hi   2,383,872
    //  33898496   rgn_lo   2,383,872   -> scratch ends 36,282,368
    //  36282368   S_big    7,372,800  fp32 [1600][1152]  [dead after softmax]
    //   8388608   hbuf    75,497,472  (gemm1 output; overlaps dead regions)
    char* ws = (char*)d_ws;
    unsigned short* wsc_bf = (unsigned short*)(ws + 0);
    unsigned short* wsh_bf = (unsigned short*)(ws + 2097152);
    unsigned short* w1_bf  = (unsigned short*)(ws + 4194304);
    unsigned short* w2_bf  = (unsigned short*)(ws + 6291456);
    unsigned short* attn   = (unsigned short*)(ws + 11796480);
    unsigned short* P_sct  = (unsigned short*)(ws + 16515072);
    unsigned short* P_sht  = (unsigned short*)(ws + 20709376);
    unsigned short* wrd_hi = (unsigned short*)(ws + 24903680);
    unsigned short* wrd_lo = (unsigned short*)(ws + 28209152);
    unsigned short* rgn_hi = (unsigned short*)(ws + 31514624);
    unsigned short* rgn_lo = (unsigned short*)(ws + 33898496);
    float*          S_big  = (float*)(ws + 36282368);
    unsigned short* hbuf   = (unsigned short*)(ws + 8388608);
    unsigned short* xbuf   = (unsigned short*)d_out;  // bf16 x inside fp32 out buf

    CvtJobs jobs;
    jobs.j[0] = { w_scale, wsc_bf, ND * ND / 2, ND * ND / 2 };
    jobs.j[1] = { w_shift, wsh_bf, ND * ND / 2, ND * ND / 2 };
    jobs.j[2] = { w1,      w1_bf,  ND * ND / 2, ND * ND / 2 };
    jobs.j[3] = { w2,      w2_bf,  ND * ND / 2, ND * ND / 2 };
    HlJobs hjobs;
    hjobs.j[0] = { wrd, wrd_hi, wrd_lo, NC * NL * ND / 2 };
    hjobs.j[1] = { rgn, rgn_hi, rgn_lo, NI * NQ * ND / 2 };
    k_cvt<<<dim3(128, 6), 256, 0, stream>>>(jobs, hjobs);

    // merged: scores GEMM (117 blocks) + P GEMMs (208 blocks), co-scheduled
    k_mid<<<325, 256, 0, stream>>>(wrd_hi, wrd_lo, rgn_hi, rgn_lo,
                                   wsc_bf, wsh_bf, S_big, P_sct, P_sht);

    k_softmax<<<NC * NI, 256, 0, stream>>>(S_big, lens, attn);

    k_attn_gemm<<<dim3(8, 9, 32), 256, 0, stream>>>(attn, P_sct, P_sht,
                                                    b_scale, b_shift, rgn, xbuf);

    // 2304 blocks, XCD-grouped swizzle (decode inside kernel); MINW=4 A/B
    k_gemm<1, 4><<<2304, 256, 0, stream>>>(xbuf, w1_bf, b1, rgn, hbuf);
    k_gemm<2, 4><<<2304, 256, 0, stream>>>(hbuf, w2_bf, b2, rgn, outf);
}